// Round 9
// baseline (270.222 us; speedup 1.0000x reference)
//
#include <hip/hip_runtime.h>
#include <hip/hip_fp16.h>

// GCN 2-layer: out = S·relu(S·(x·W1)+b1)·W2 + b2, S = D^-1/2 (A+I) D^-1/2
// R9: fp16 gather tables (3.2MB, fits per-XCD L2), non-temporal CSR stream,
// 8-deep gather pipeline in agg, EPB halved for binning occupancy.
// Sort pipeline otherwise unchanged from R8.

constexpr int BKT_BITS = 8;
constexpr int BKT = 1 << BKT_BITS;   // nodes per bucket
constexpr int EPB = 8192;            // edges per binning block

__device__ __forceinline__ unsigned long long nt_load_u64(const void* p) {
  return __builtin_nontemporal_load((const unsigned long long*)p);
}

// ---- fused: x@W1 (blocks [0, xw1b)) + dst histogram (blocks [xw1b, ...)) --
__global__ __launch_bounds__(256) void k_pre(
    const float* __restrict__ x, const float* __restrict__ W1,
    float* __restrict__ h1pre, int n,
    const int* __restrict__ dst, int* __restrict__ hist, int ne, int nb,
    int xw1b) {
  __shared__ float W1t[16 * 512];          // 32 KB; hist path reuses as int[]
  if ((int)blockIdx.x >= xw1b) {
    int* sh = (int*)W1t;
    int hb = blockIdx.x - xw1b;
    for (int i = threadIdx.x; i < nb; i += 256) sh[i] = 0;
    __syncthreads();
    int base = hb * EPB;
    int end = min(base + EPB, ne);
    for (int e = base + threadIdx.x; e < end; e += 256)
      atomicAdd(&sh[dst[e] >> BKT_BITS], 1);
    __syncthreads();
    for (int i = threadIdx.x; i < nb; i += 256) hist[hb * nb + i] = sh[i];
    return;
  }
  {
#pragma unroll
    for (int i = 0; i < 32; ++i) {
      int idx = threadIdx.x + i * 256;     // source flat index = k*16 + j
      int k = idx >> 4, j = idx & 15;
      W1t[j * 512 + k] = W1[idx];
    }
  }
  __syncthreads();
  int gtid = blockIdx.x * 256 + threadIdx.x;
  int rp = gtid >> 2, q = gtid & 3;
  int r0 = rp * 2;
  if (r0 >= n) return;
  int r1 = r0 + 1;
  bool has1 = (r1 < n);
  const float4* x4 = (const float4*)x;
  const float4* W1t4 = (const float4*)W1t;
  float acc0[16], acc1[16];
#pragma unroll
  for (int j = 0; j < 16; ++j) { acc0[j] = 0.f; acc1[j] = 0.f; }
  long rb0 = (long)r0 * 128 + q;
  long rb1 = (long)r1 * 128 + q;
  for (int m = 0; m < 32; ++m) {
    float4 a = x4[rb0 + m * 4];
    float4 b = has1 ? x4[rb1 + m * 4] : make_float4(0.f, 0.f, 0.f, 0.f);
    int p = q + m * 4;
#pragma unroll
    for (int j = 0; j < 16; ++j) {
      float4 w = W1t4[j * 128 + p];
      acc0[j] = fmaf(a.x, w.x, acc0[j]);
      acc0[j] = fmaf(a.y, w.y, acc0[j]);
      acc0[j] = fmaf(a.z, w.z, acc0[j]);
      acc0[j] = fmaf(a.w, w.w, acc0[j]);
      acc1[j] = fmaf(b.x, w.x, acc1[j]);
      acc1[j] = fmaf(b.y, w.y, acc1[j]);
      acc1[j] = fmaf(b.z, w.z, acc1[j]);
      acc1[j] = fmaf(b.w, w.w, acc1[j]);
    }
  }
#pragma unroll
  for (int j = 0; j < 16; ++j) {
    acc0[j] += __shfl_xor(acc0[j], 1);
    acc0[j] += __shfl_xor(acc0[j], 2);
    acc1[j] += __shfl_xor(acc1[j], 1);
    acc1[j] += __shfl_xor(acc1[j], 2);
  }
  if (q == 0) {
    float4* o4 = (float4*)h1pre;
#pragma unroll
    for (int j4 = 0; j4 < 4; ++j4) {
      o4[(long)r0 * 4 + j4] =
          make_float4(acc0[4 * j4], acc0[4 * j4 + 1], acc0[4 * j4 + 2], acc0[4 * j4 + 3]);
      if (has1)
        o4[(long)r1 * 4 + j4] =
            make_float4(acc1[4 * j4], acc1[4 * j4 + 1], acc1[4 * j4 + 2], acc1[4 * j4 + 3]);
    }
  }
}

// ---- pass 2a: per-bucket scan over binning blocks -------------------------
__global__ __launch_bounds__(256) void k_colscan(
    const int* __restrict__ hist, int* __restrict__ basep,
    int* __restrict__ colsum, int nblk, int nb) {
  __shared__ int sh[256];
  __shared__ int carry_s;
  int k = blockIdx.x;
  int t = threadIdx.x;
  if (t == 0) carry_s = 0;
  __syncthreads();
  for (int c0 = 0; c0 < nblk; c0 += 256) {
    int b = c0 + t;
    int v = (b < nblk) ? hist[b * nb + k] : 0;
    sh[t] = v;
    __syncthreads();
    for (int d = 1; d < 256; d <<= 1) {
      int u = (t >= d) ? sh[t - d] : 0;
      __syncthreads();
      sh[t] += u;
      __syncthreads();
    }
    if (b < nblk) basep[b * nb + k] = carry_s + sh[t] - v;
    __syncthreads();
    if (t == 0) carry_s += sh[255];
    __syncthreads();
  }
  if (t == 0) colsum[k] = carry_s;
}

// ---- pass 2b: exclusive scan over buckets (single block, LDS) -------------
__global__ __launch_bounds__(256) void k_scanb(
    const int* __restrict__ colsum, int* __restrict__ bstart, int nb) {
  __shared__ int sh[256];
  __shared__ int carry_s;
  int t = threadIdx.x;
  if (t == 0) carry_s = 0;
  __syncthreads();
  for (int c0 = 0; c0 < nb; c0 += 256) {
    int k = c0 + t;
    int v = (k < nb) ? colsum[k] : 0;
    sh[t] = v;
    __syncthreads();
    for (int d = 1; d < 256; d <<= 1) {
      int u = (t >= d) ? sh[t - d] : 0;
      __syncthreads();
      sh[t] += u;
      __syncthreads();
    }
    if (k < nb) bstart[k] = carry_s + sh[t] - v;
    __syncthreads();
    if (t == 0) carry_s += sh[255];
    __syncthreads();
  }
  if (t == 0) bstart[nb] = carry_s;
}

// ---- pass 3: scatter records to bucket-contiguous array -------------------
__global__ __launch_bounds__(256) void k_binfill(
    const int* __restrict__ ei, const float* __restrict__ ew,
    const int* __restrict__ basep, const int* __restrict__ bstart,
    uint2* __restrict__ recs, int ne, int nb) {
  extern __shared__ int cur[];
  for (int i = threadIdx.x; i < nb; i += 256)
    cur[i] = basep[blockIdx.x * nb + i] + bstart[i];
  __syncthreads();
  int bs = blockIdx.x * EPB;
  int end = min(bs + EPB, ne);
  for (int e = bs + threadIdx.x; e < end; e += 256) {
    int s = ei[e];
    int d = ei[ne + e];
    float w = ew[e];
    int bkt = d >> BKT_BITS;
    int pos = atomicAdd(&cur[bkt], 1);
    recs[pos] = make_uint2((unsigned)s | ((unsigned)(d & (BKT - 1)) << 20),
                           __float_as_uint(w));
  }
}

// ---- pass 4: bucket -> per-node CSR + rowptr + dinv + f16 table -----------
__global__ __launch_bounds__(256) void k_csr(
    const uint2* __restrict__ recs, const int* __restrict__ bstart,
    uint2* __restrict__ csr, int* __restrict__ rowptr,
    float* __restrict__ dinv, const float* __restrict__ h1pre,
    __half2* __restrict__ hp16, int n, int ne) {
  __shared__ float sdeg[BKT];
  __shared__ int soff[BKT];
  __shared__ int scur[BKT];
  int t = threadIdx.x;
  sdeg[t] = 0.f;
  soff[t] = 0;
  __syncthreads();
  int k = blockIdx.x;
  int s0 = bstart[k], s1 = bstart[k + 1];
  for (int e = s0 + t; e < s1; e += 256) {
    uint2 r = recs[e];
    int dl = (r.x >> 20) & (BKT - 1);
    atomicAdd(&soff[dl], 1);
    atomicAdd(&sdeg[dl], __uint_as_float(r.y));
  }
  __syncthreads();
  int v = soff[t];
  for (int d = 1; d < BKT; d <<= 1) {
    int u = (t >= d) ? soff[t - d] : 0;
    __syncthreads();
    soff[t] += u;
    __syncthreads();
  }
  int excl = soff[t] - v;
  scur[t] = excl;
  int node = (k << BKT_BITS) + t;
  float dvv = 0.f;
  if (node < n) {
    dvv = 1.0f / sqrtf(sdeg[t] + 1.0f);
    rowptr[node] = s0 + excl;
    dinv[node] = dvv;
  }
  sdeg[t] = dvv;                 // reuse: per-node dinv for the table loop
  if (k == 0 && t == 0) rowptr[n] = ne;
  __syncthreads();
  for (int e = s0 + t; e < s1; e += 256) {
    uint2 r = recs[e];
    int dl = (r.x >> 20) & (BKT - 1);
    int pos = s0 + atomicAdd(&scur[dl], 1);
    csr[pos] = make_uint2(r.x & 0xFFFFF, r.y);
  }
  // fused: hp16[node][:] = f16(dinv[node] * h1pre[node][:])  (coalesced)
  int nbase = k << BKT_BITS;
  int nn = min(n - nbase, BKT);
  if (nn > 0) {
    const float2* hf2 = (const float2*)h1pre + (long)nbase * 8;
    __half2* hp2 = hp16 + (long)nbase * 8;
    int lim2 = nn * 8;
    for (int i = t; i < lim2; i += 256) {
      float dv2 = sdeg[i >> 3];
      float2 hv = hf2[i];
      hp2[i] = __floats2half2_rn(hv.x * dv2, hv.y * dv2);
    }
  }
}

// ---- node-major gather-aggregate over CSR (4 lanes/node, f16 table) -------
// hin2 = f16(dinv*h). acc = h'[node] + sum_e w*h'[src]; v = dv*acc.
// MODE 1: outv (half2*) <- f16(dv*relu(v + b1))     (layer-1 table)
// MODE 2: outv (float*) <- v @ W2 + b2              (final output)
template <int MODE>
__global__ __launch_bounds__(256) void k_agg(
    const __half2* __restrict__ hin2, const uint2* __restrict__ csr,
    const int* __restrict__ rowptr, const float* __restrict__ dinv,
    const float* __restrict__ bias, const float* __restrict__ W2,
    void* __restrict__ outv, int n) {
  __shared__ float W2s[MODE == 2 ? 16 * 64 : 1];
  __shared__ float accs[MODE == 2 ? 64 * 16 : 1];
  if (MODE == 2) {
#pragma unroll
    for (int s = 0; s < 4; ++s) W2s[threadIdx.x + s * 256] = W2[threadIdx.x + s * 256];
  }
  int gtid = blockIdx.x * 256 + threadIdx.x;
  int node = gtid >> 2, q = gtid & 3;
  bool valid = node < n;
  float4 acc = make_float4(0.f, 0.f, 0.f, 0.f);
  float dv = 0.f;
  if (valid) {
    dv = dinv[node];
    int hb = (node << 3) + (q << 1);
    {
      float2 f0 = __half22float2(hin2[hb]);
      float2 f1 = __half22float2(hin2[hb + 1]);
      acc = make_float4(f0.x, f0.y, f1.x, f1.y);   // self term h'[node]
    }
    int e = rowptr[node], e1 = rowptr[node + 1];
    for (; e + 7 < e1; e += 8) {
      unsigned long long rv[8];
#pragma unroll
      for (int u = 0; u < 8; ++u) rv[u] = nt_load_u64(&csr[e + u]);
      float2 g0[8], g1[8];
      float wv[8];
#pragma unroll
      for (int u = 0; u < 8; ++u) {
        int src = (int)(unsigned)rv[u];
        wv[u] = __uint_as_float((unsigned)(rv[u] >> 32));
        int b = (src << 3) + (q << 1);
        g0[u] = __half22float2(hin2[b]);
        g1[u] = __half22float2(hin2[b + 1]);
      }
#pragma unroll
      for (int u = 0; u < 8; ++u) {
        acc.x = fmaf(wv[u], g0[u].x, acc.x);
        acc.y = fmaf(wv[u], g0[u].y, acc.y);
        acc.z = fmaf(wv[u], g1[u].x, acc.z);
        acc.w = fmaf(wv[u], g1[u].y, acc.w);
      }
    }
    for (; e < e1; ++e) {
      unsigned long long rv = nt_load_u64(&csr[e]);
      int src = (int)(unsigned)rv;
      float w = __uint_as_float((unsigned)(rv >> 32));
      int b = (src << 3) + (q << 1);
      float2 f0 = __half22float2(hin2[b]);
      float2 f1 = __half22float2(hin2[b + 1]);
      acc.x = fmaf(w, f0.x, acc.x);
      acc.y = fmaf(w, f0.y, acc.y);
      acc.z = fmaf(w, f1.x, acc.z);
      acc.w = fmaf(w, f1.y, acc.w);
    }
    acc.x *= dv; acc.y *= dv; acc.z *= dv; acc.w *= dv;   // v = dv*acc
  }
  if (MODE == 1) {
    if (valid) {
      float4 b = ((const float4*)bias)[q];
      __half2* o2 = (__half2*)outv;
      int hb = (node << 3) + (q << 1);
      o2[hb] = __floats2half2_rn(dv * fmaxf(acc.x + b.x, 0.f),
                                 dv * fmaxf(acc.y + b.y, 0.f));
      o2[hb + 1] = __floats2half2_rn(dv * fmaxf(acc.z + b.z, 0.f),
                                     dv * fmaxf(acc.w + b.w, 0.f));
    }
    return;
  }
  // MODE 2: LDS-staged 16x64 W2 epilogue (64 nodes per block)
  ((float4*)accs)[threadIdx.x] = acc;
  __syncthreads();
  const float4* W2s4 = (const float4*)W2s;
  float* out = (float*)outv;
#pragma unroll
  for (int it = 0; it < 4; ++it) {
    int nl = it * 16 + (threadIdx.x >> 4);
    int o4 = threadIdx.x & 15;
    int node2 = blockIdx.x * 64 + nl;
    if (node2 < n) {
      float4 v = ((const float4*)bias)[o4];
#pragma unroll
      for (int jj = 0; jj < 16; ++jj) {
        float a = accs[nl * 16 + jj];
        float4 w = W2s4[jj * 16 + o4];
        v.x = fmaf(a, w.x, v.x);
        v.y = fmaf(a, w.y, v.y);
        v.z = fmaf(a, w.z, v.z);
        v.w = fmaf(a, w.w, v.w);
      }
      ((float4*)out)[(long)node2 * 16 + o4] = v;
    }
  }
}

extern "C" void kernel_launch(void* const* d_in, const int* in_sizes, int n_in,
                              void* d_out, int out_size, void* d_ws, size_t ws_size,
                              hipStream_t stream) {
  const float* x  = (const float*)d_in[0];
  const int*   ei = (const int*)d_in[1];
  const float* ew = (const float*)d_in[2];
  const float* W1 = (const float*)d_in[3];
  const float* b1 = (const float*)d_in[4];
  const float* W2 = (const float*)d_in[5];
  const float* b2 = (const float*)d_in[6];
  float* out = (float*)d_out;
  int n  = in_sizes[0] / 512;
  int ne = in_sizes[1] / 2;

  int nb   = (n + BKT - 1) >> BKT_BITS;      // buckets (391)
  int nblk = (ne + EPB - 1) / EPB;           // binning blocks (391)

  char* ws = (char*)d_ws;
  size_t off = 0;
  auto alloc = [&](size_t bytes) {
    size_t r = off;
    off += (bytes + 255) & ~(size_t)255;
    return r;
  };
  float*   dinv   = (float*)  (ws + alloc((size_t)n * 4));
  float*   h1pre  = (float*)  (ws + alloc((size_t)n * 16 * 4));
  __half2* hp16   = (__half2*)(ws + alloc((size_t)n * 16 * 2));
  __half2* h1p16  = (__half2*)(ws + alloc((size_t)n * 16 * 2));
  uint2*   recs   = (uint2*)  (ws + alloc((size_t)ne * 8));
  uint2*   csr    = (uint2*)  (ws + alloc((size_t)ne * 8));
  int*     rowptr = (int*)    (ws + alloc((size_t)(n + 1) * 4));
  int*     hist   = (int*)    (ws + alloc((size_t)nblk * nb * 4));
  int*     basep  = (int*)    (ws + alloc((size_t)nblk * nb * 4));
  int*     colsum = (int*)    (ws + alloc((size_t)nb * 4));
  int*     bstart = (int*)    (ws + alloc((size_t)(nb + 1) * 4));
  (void)ws_size; (void)n_in; (void)out_size;

  int nrp = (n + 1) / 2;
  int xw1b = (nrp * 4 + 255) / 256;
  k_pre<<<xw1b + nblk, 256, 0, stream>>>(x, W1, h1pre, n, ei + ne, hist, ne, nb, xw1b);

  k_colscan<<<nb, 256, 0, stream>>>(hist, basep, colsum, nblk, nb);
  k_scanb<<<1, 256, 0, stream>>>(colsum, bstart, nb);
  size_t shb = (size_t)nb * 4;
  k_binfill<<<nblk, 256, shb, stream>>>(ei, ew, basep, bstart, recs, ne, nb);
  k_csr<<<nb, 256, 0, stream>>>(recs, bstart, csr, rowptr, dinv, h1pre, hp16, n, ne);

  int gN4 = (n * 4 + 255) / 256;
  k_agg<1><<<gN4, 256, 0, stream>>>(hp16, csr, rowptr, dinv, b1, nullptr, h1p16, n);
  k_agg<2><<<gN4, 256, 0, stream>>>(h1p16, csr, rowptr, dinv, b2, W2, out, n);
}